// Round 13
// baseline (319.271 us; speedup 1.0000x reference)
//
#include <hip/hip_runtime.h>
#include <hip/hip_bf16.h>

// SoftMoE fp16-MFMA pipeline. B=4 L=2048 D=1024 H=16 S=512 E=8 FF=4096 DH=64
#define B_  4
#define L_  2048
#define D_  1024
#define H_  16
#define S_  512
#define E_  8
#define FF_ 4096
#define DH_ 64

typedef _Float16 half8 __attribute__((ext_vector_type(8)));
typedef _Float16 half4v __attribute__((ext_vector_type(4)));
typedef float floatx4 __attribute__((ext_vector_type(4)));
typedef unsigned short u16;

__device__ inline u16 f2h(float v) {
  _Float16 x = (_Float16)v;
  return __builtin_bit_cast(u16, x);
}

__device__ inline void gload_lds16(const void* g, void* l) {
  __builtin_amdgcn_global_load_lds(
      (const __attribute__((address_space(1))) void*)g,
      (__attribute__((address_space(3))) void*)l, 16, 0, 0);
}

// swizzled index (u16 units): row stride 64 halfs (128B), XOR 16B granule by row&7
__device__ inline int swz(int row, int colh) {  // colh multiple of 8
  return row * 64 + (colh ^ ((row & 7) << 3));
}
__device__ inline int swz1(int row, int colh) { // arbitrary colh
  return row * 64 + ((colh & ~7) ^ ((row & 7) << 3)) + (colh & 7);
}

// ---------------- Fused LayerNorm + weight cvt -------------------------------
// blocks 0..8191: LN row -> fp16. blocks 8192..10239: cvt wk|wv|wq|sq*0.125|skq.
__global__ __launch_bounds__(256) void ln_wcvt(const float* __restrict__ x,
    const float* __restrict__ w, const float* __restrict__ bb,
    u16* __restrict__ xn,
    const float* __restrict__ w0, const float* __restrict__ w1,
    const float* __restrict__ w2, const float* __restrict__ sq,
    const float* __restrict__ skq, u16* __restrict__ dst) {
  int tid = threadIdx.x;
  if (blockIdx.x >= 8192) {
    long i = ((long)(blockIdx.x - 8192) * 256 + tid) * 8;
    const float* src; long off; float sc = 1.0f;
    if (i < 3145728) {
      int wsel = (int)(i >> 20);
      src = (wsel == 0) ? w0 : (wsel == 1) ? w1 : w2;
      off = i & 1048575;
    } else if (i < 3670016) {
      src = sq; off = i - 3145728; sc = 0.125f;
    } else {
      src = skq; off = i - 3670016;
    }
    float4 a = *(const float4*)(src + off);
    float4 b = *(const float4*)(src + off + 4);
    half8 h = { (_Float16)(a.x*sc), (_Float16)(a.y*sc), (_Float16)(a.z*sc), (_Float16)(a.w*sc),
                (_Float16)(b.x*sc), (_Float16)(b.y*sc), (_Float16)(b.z*sc), (_Float16)(b.w*sc) };
    *(half8*)(dst + i) = h;
    return;
  }
  int row = blockIdx.x;
  float4 v = ((const float4*)(x + (long)row * D_))[tid];
  float s = v.x + v.y + v.z + v.w;
  __shared__ float red[4];
  #pragma unroll
  for (int off = 32; off > 0; off >>= 1) s += __shfl_down(s, off);
  int wid = tid >> 6, lane = tid & 63;
  if (lane == 0) red[wid] = s;
  __syncthreads();
  float mean = (red[0] + red[1] + red[2] + red[3]) * (1.0f / D_);
  __syncthreads();
  float dx = v.x - mean, dy = v.y - mean, dz = v.z - mean, dw = v.w - mean;
  float s2 = dx*dx + dy*dy + dz*dz + dw*dw;
  #pragma unroll
  for (int off = 32; off > 0; off >>= 1) s2 += __shfl_down(s2, off);
  if (lane == 0) red[wid] = s2;
  __syncthreads();
  float var = (red[0] + red[1] + red[2] + red[3]) * (1.0f / D_);
  float rstd = rsqrtf(var + 1e-5f);
  float4 wv = ((const float4*)w)[tid];
  float4 bv = ((const float4*)bb)[tid];
  half4v o = { (_Float16)(dx * rstd * wv.x + bv.x),
               (_Float16)(dy * rstd * wv.y + bv.y),
               (_Float16)(dz * rstd * wv.z + bv.z),
               (_Float16)(dw * rstd * wv.w + bv.w) };
  *(half4v*)&xn[(long)row * D_ + tid * 4] = o;
}

// ---------------- Fused projections (fp16 weights, dbuf 2-phase, BK=64) ------
// grid (64 m, 24): wsel = by>>3 (k,v,q); n0 = (by&7)*128; m0 = bx*128.
// BK=64: 16 K-steps, 32 barriers (halved vs BK=32). LDS 64 KB dbuf.
// Swizzle both-sides: 8-chunk XOR by row&7 (store source chunk = (l&7)^(row&7);
// read slot = (ks*4+g)^(row&7)) -> uniform lane spread on ds_read_b128.
__global__ __launch_bounds__(256) void proj_f16(
    const u16* __restrict__ A, const u16* __restrict__ Wc,
    u16* __restrict__ kh, u16* __restrict__ vT, u16* __restrict__ qh) {
  const int wsel = blockIdx.y >> 3;
  const int n0 = (blockIdx.y & 7) * 128, m0 = blockIdx.x * 128;
  const u16* Bh = Wc + (long)wsel * 1048576;
  const int tid = threadIdx.x, l = tid & 63, w = tid >> 6;
  const int wr = w >> 1, wc = w & 1;
  const int lq = l & 15, g = l >> 4;
  __shared__ __align__(16) u16 As[2][128 * 64];
  __shared__ __align__(16) u16 Bs[2][128 * 64];
  floatx4 acc[4][4] = {};

  // staging: wave w covers rows [w*32, w*32+32), 4 octets of 8 rows each.
  // thread handles row w*32+o*8+(l>>3), LDS slot l&7, source chunk (l&7)^(l>>3).
  const int srow = l >> 3;
  const int sch = ((l & 7) ^ srow) * 8;
  long aoff[4], boff[4];
  #pragma unroll
  for (int o = 0; o < 4; ++o) {
    aoff[o] = (long)(m0 + w * 32 + o * 8 + srow) * D_ + sch;
    boff[o] = (long)(n0 + w * 32 + o * 8 + srow) * D_ + sch;
  }

  #define PSTAGE(buf, kt)                                                     \
    do {                                                                      \
      _Pragma("unroll")                                                       \
      for (int o = 0; o < 4; ++o) {                                           \
        gload_lds16(A + aoff[o] + (kt), &As[buf][(w * 32 + o * 8) * 64]);     \
        gload_lds16(Bh + boff[o] + (kt), &Bs[buf][(w * 32 + o * 8) * 64]);    \
      }                                                                       \
    } while (0)

  PSTAGE(0, 0);
  __syncthreads();

  int cur = 0;
  for (int t = 0; t < 16; ++t) {
    if (t < 15) PSTAGE(cur ^ 1, (t + 1) * 64);
    #pragma unroll
    for (int ks = 0; ks < 2; ++ks) {
      half8 af[4], bfr[4];
      #pragma unroll
      for (int fr = 0; fr < 4; ++fr) {
        int row = wr * 64 + fr * 16 + lq;
        af[fr] = *(const half8*)&As[cur][row * 64 + (((ks * 4 + g) ^ (row & 7)) << 3)];
      }
      #pragma unroll
      for (int fc = 0; fc < 4; ++fc) {
        int rr = wc * 64 + fc * 16 + lq;
        bfr[fc] = *(const half8*)&Bs[cur][rr * 64 + (((ks * 4 + g) ^ (rr & 7)) << 3)];
      }
      #pragma unroll
      for (int fr = 0; fr < 4; ++fr)
        #pragma unroll
        for (int fc = 0; fc < 4; ++fc)
          acc[fr][fc] = __builtin_amdgcn_mfma_f32_16x16x32_f16(af[fr], bfr[fc], acc[fr][fc], 0, 0, 0);
    }
    __syncthreads();
    cur ^= 1;
  }
  #undef PSTAGE

  if (wsel == 1) {
    #pragma unroll
    for (int fr = 0; fr < 4; ++fr)
      #pragma unroll
      for (int fc = 0; fc < 4; ++fc) {
        int row = m0 + wr * 64 + fr * 16 + g * 4;
        int col = n0 + wc * 64 + fc * 16 + lq;
        half4v o = { (_Float16)acc[fr][fc][0], (_Float16)acc[fr][fc][1],
                     (_Float16)acc[fr][fc][2], (_Float16)acc[fr][fc][3] };
        long idx = ((long)(row >> 11) * 1024 + col) * 2048 + (row & 2047);
        *(half4v*)&vT[idx] = o;
      }
  } else {
    u16* C = (wsel == 0) ? kh : qh;
    const float sc = (wsel == 2) ? 0.125f : 1.0f;
    #pragma unroll
    for (int fr = 0; fr < 4; ++fr)
      #pragma unroll
      for (int fc = 0; fc < 4; ++fc)
        #pragma unroll
        for (int r = 0; r < 4; ++r) {
          int row = m0 + wr * 64 + fr * 16 + g * 4 + r;
          int col = n0 + wc * 64 + fc * 16 + lq;
          C[(long)row * D_ + col] = f2h(acc[fr][fc][r] * sc);
        }
  }
}

// ---------------- Expert GEMM: ring-3 LDS, counted vmcnt ---------------------
template<int MODE>
__global__ __launch_bounds__(512) void expert_gemm(
    const u16* __restrict__ A, const float* __restrict__ Bw,
    const float* __restrict__ bias, u16* __restrict__ Ch,
    float* __restrict__ Cp) {
  constexpr int LDA = (MODE == 1) ? D_ : FF_;
  constexpr int LDB = (MODE == 1) ? D_ : FF_;
  const int e = blockIdx.z;
  const int n0 = blockIdx.x * 64;
  const int kc0 = (MODE == 2) ? blockIdx.y * 1024 : 0;
  const int tid = threadIdx.x, l = tid & 63, w = tid >> 6;
  const int wm = w >> 1, wn = w & 1;
  const int lr = l & 15, q = l >> 4;

  __shared__ __align__(16) u16  As[3][256 * 32];
  __shared__ __align__(16) float Bs[3][64 * 32];

  long asrc[2];
  #pragma unroll
  for (int i = 0; i < 2; ++i) {
    int ar = w * 32 + i * 16 + (l >> 2);
    long grow = (MODE == 1) ? ((long)(ar >> 6) * 512 + e * 64 + (ar & 63))
                            : (((long)(ar >> 6) * 8 + e) * 64 + (ar & 63));
    int ck = (l & 3) ^ (ar & 3);
    asrc[i] = grow * (long)LDA + kc0 + ck * 8;
  }
  const float* Bp = Bw + (long)e * (D_ * FF_);
  int brow = w * 8 + (l >> 3);
  int bck = (l & 7) ^ (brow & 7);
  long bsrc = (long)(n0 + brow) * LDB + kc0 + bck * 4;

  floatx4 acc[4][2] = {};

  #define STAGE(buf, kt)                                                 \
    do {                                                                 \
      gload_lds16(A + asrc[0] + (kt), &As[buf][(w * 32) * 32]);          \
      gload_lds16(A + asrc[1] + (kt), &As[buf][(w * 32 + 16) * 32]);     \
      gload_lds16(Bp + bsrc + (kt), &Bs[buf][(w * 8) * 32]);             \
    } while (0)

  STAGE(0, 0);
  STAGE(1, 32);

  int c0 = 0, c1 = 1, c2 = 2;
  for (int t = 0; t < 32; ++t) {
    if (t < 31) asm volatile("s_waitcnt vmcnt(3)" ::: "memory");
    else        asm volatile("s_waitcnt vmcnt(0)" ::: "memory");
    __builtin_amdgcn_s_barrier();
    if (t + 2 < 32) STAGE(c2, (t + 2) * 32);

    half8 af[4];
    #pragma unroll
    for (int fr = 0; fr < 4; ++fr) {
      int row = wm * 64 + fr * 16 + lr;
      af[fr] = *(const half8*)&As[c0][row * 32 + ((q ^ (row & 3)) << 3)];
    }
    half8 bf[2];
    #pragma unroll
    for (int fc = 0; fc < 2; ++fc) {
      int rn = wn * 32 + fc * 16 + lr;
      float4 x0 = *(const float4*)&Bs[c0][rn * 32 + (((2 * q) ^ (rn & 7)) << 2)];
      float4 x1 = *(const float4*)&Bs[c0][rn * 32 + (((2 * q + 1) ^ (rn & 7)) << 2)];
      bf[fc] = (half8){ (_Float16)x0.x, (_Float16)x0.y, (_Float16)x0.z, (_Float16)x0.w,
                        (_Float16)x1.x, (_Float16)x1.y, (_Float16)x1.z, (_Float16)x1.w };
    }
    #pragma unroll
    for (int fr = 0; fr < 4; ++fr)
      #pragma unroll
      for (int fc = 0; fc < 2; ++fc)
        acc[fr][fc] = __builtin_amdgcn_mfma_f32_16x16x32_f16(af[fr], bf[fc], acc[fr][fc], 0, 0, 0);

    int tmp = c0; c0 = c1; c1 = c2; c2 = tmp;
  }
  #undef STAGE

  #pragma unroll
  for (int fr = 0; fr < 4; ++fr)
    #pragma unroll
    for (int fc = 0; fc < 2; ++fc)
      #pragma unroll
      for (int r = 0; r < 4; ++r) {
        int ar = wm * 64 + fr * 16 + q * 4 + r;
        int col = n0 + wn * 32 + fc * 16 + lr;
        float val = acc[fr][fc][r];
        if constexpr (MODE == 1) {
          val += bias[e * FF_ + col];
          val = fmaxf(val, 0.f);
          val *= val;
          Ch[(((long)(ar >> 6) * 8 + e) * 64 + (ar & 63)) * FF_ + col] = f2h(val);
        } else {
          Cp[(((long)blockIdx.y * 8 + e) * 256 + ar) * 1024 + col] = val;
        }
      }
}

// ---------------- expert-out reduce: partials+bias -> eoT (transposed f16) ---
__global__ __launch_bounds__(256) void eo_reduce(const float* __restrict__ pb,
    const float* __restrict__ b_out, u16* __restrict__ eoT) {
  long j4 = (long)blockIdx.x * 256 + threadIdx.x;
  long j = j4 * 4;
  float4 s = ((const float4*)pb)[j4];
  #pragma unroll
  for (int c = 1; c < 4; ++c) {
    float4 t = ((const float4*)(pb + (long)c * 2097152))[j4];
    s.x += t.x; s.y += t.y; s.z += t.z; s.w += t.w;
  }
  int e = (int)(j >> 18);
  int rem = (int)(j & 262143);
  int row = rem >> 10, col = rem & 1023;
  float4 bv = *(const float4*)(b_out + e * 1024 + col);
  s.x += bv.x; s.y += bv.y; s.z += bv.z; s.w += bv.w;
  int b = row >> 6;
  int slot = e * 64 + (row & 63);
  float sv[4] = { s.x, s.y, s.z, s.w };
  #pragma unroll
  for (int i = 0; i < 4; ++i) {
    long idx = ((long)b * 1024 + col + i) * 512 + slot;
    eoT[idx] = f2h(sv[i]);
  }
}

// ---------------- MFMA flash attention v2: register-resident P ---------------
template<bool OF32>
__global__ __launch_bounds__(256) void flash_f16(
    const u16* __restrict__ Qg, long qB, long qH, long qR,
    const u16* __restrict__ Kg, long kB, long kH, long kR,
    const u16* __restrict__ VTg, long vB, long vH, long vR,
    void* __restrict__ Og, long oB, long oH, long oR,
    float* __restrict__ pd, float* __restrict__ pacc,
    int Nq, int Nk, int nC) {
  __shared__ __align__(16) u16 Ks[64 * 64];
  __shared__ __align__(16) u16 Vt[64 * 64];
  const int tid = threadIdx.x, l = tid & 63, w = tid >> 6;
  const int g = l >> 4, lq = l & 15;
  const int bh = blockIdx.z, b = bh >> 4, hd = bh & 15;
  const int q0 = blockIdx.x * 64 + w * 16;
  const int chunk = Nk / nC, k0 = blockIdx.y * chunk;

  half8 qf[2];
  #pragma unroll
  for (int ks = 0; ks < 2; ++ks)
    qf[ks] = *(const half8*)(Qg + b * qB + hd * qH +
                             (long)(q0 + lq) * qR + ks * 32 + g * 8);

  const int srow = l >> 3;
  const int scol = ((l & 7) ^ srow) * 8;
  const long kbase = b * kB + hd * kH;
  const long vbase = b * vB + hd * vH;

  float lrun = 0.f;
  floatx4 o[4] = {};

  for (int t = 0; t < chunk; t += 64) {
    #pragma unroll
    for (int i = 0; i < 2; ++i) {
      int u = i * 4 + w;
      gload_lds16(Kg + kbase + (long)(k0 + t + u * 8 + srow) * kR + scol,
                  &Ks[u * 8 * 64]);
      gload_lds16(VTg + vbase + (long)(u * 8 + srow) * vR + k0 + t + scol,
                  &Vt[u * 8 * 64]);
    }
    __syncthreads();

    floatx4 s[4];
    #pragma unroll
    for (int j = 0; j < 4; ++j) s[j] = (floatx4){0.f, 0.f, 0.f, 0.f};
    #pragma unroll
    for (int ks = 0; ks < 2; ++ks)
      #pragma unroll
      for (int j = 0; j < 4; ++j) {
        half8 kf = *(const half8*)&Ks[swz(j * 16 + lq, ks * 32 + g * 8)];
        s[j] = __builtin_amdgcn_mfma_f32_16x16x32_f16(kf, qf[ks], s[j], 0, 0, 0);
      }

    half4v pa[4];
    float rs = 0.f;
    #pragma unroll
    for (int j = 0; j < 4; ++j)
      #pragma unroll
      for (int r = 0; r < 4; ++r) {
        float p = __expf(s[j][r]);
        rs += p;
        pa[j][r] = (_Float16)p;
      }
    lrun += rs;

    #pragma unroll
    for (int j = 0; j < 4; ++j)
      #pragma unroll
      for (int n = 0; n < 4; ++n) {
        half4v vf = *(const half4v*)&Vt[swz1(n * 16 + lq, j * 16 + g * 4)];
        o[n] = __builtin_amdgcn_mfma_f32_16x16x16f16(pa[j], vf, o[n], 0, 0, 0);
      }
    __syncthreads();
  }

  lrun += __shfl_xor(lrun, 16);
  lrun += __shfl_xor(lrun, 32);

  if (nC == 1) {
    float inv = 1.0f / lrun;
    float invr[4];
    #pragma unroll
    for (int r = 0; r < 4; ++r) invr[r] = __shfl(inv, g * 4 + r);
    #pragma unroll
    for (int n = 0; n < 4; ++n)
      #pragma unroll
      for (int r = 0; r < 4; ++r) {
        int row = q0 + g * 4 + r;
        int dh = n * 16 + lq;
        float val = o[n][r] * invr[r];
        long off = b * oB + hd * oH + (long)row * oR + dh;
        if (OF32) ((float*)Og)[off] = val;
        else      ((u16*)Og)[off] = f2h(val);
      }
  } else {
    if (l < 16) pd[((long)bh * Nq + q0 + l) * nC + blockIdx.y] = lrun;
    #pragma unroll
    for (int r = 0; r < 4; ++r) {
      int row = q0 + g * 4 + r;
      long idx = ((long)bh * Nq + row) * nC + blockIdx.y;
      #pragma unroll
      for (int n = 0; n < 4; ++n)
        pacc[idx * 64 + n * 16 + lq] = o[n][r];
    }
  }
}

// ---------------- Flash finalize: sum nC chunk partials -> f16 out -----------
__global__ __launch_bounds__(256) void finalize_f16(
    const float* __restrict__ pd, const float* __restrict__ pacc,
    u16* __restrict__ outp, int nC, int Nq, long oB, long oH, long oR) {
  int tid = threadIdx.x;
  int row = blockIdx.x * 4 + (tid >> 6);
  int lane = tid & 63;
  long base = (long)row * nC;
  float Dn = 0.f, a = 0.f;
  for (int c = 0; c < nC; ++c) {
    Dn += pd[base + c];
    a += pacc[(base + c) * 64 + lane];
  }
  int bh = row / Nq, qrow = row - bh * Nq;
  int b = bh >> 4, h = bh & 15;
  outp[(long)b * oB + (long)h * oH + (long)qrow * oR + lane] = f2h(a / Dn);
}

extern "C" void kernel_launch(void* const* d_in, const int* in_sizes, int n_in,
                              void* d_out, int out_size, void* d_ws, size_t ws_size,
                              hipStream_t stream) {
  const float* x     = (const float*)d_in[0];
  const float* sq    = (const float*)d_in[1];
  const float* skq   = (const float*)d_in[2];
  const float* wk    = (const float*)d_in[3];
  const float* wv    = (const float*)d_in[4];
  const float* wq    = (const float*)d_in[5];
  const float* w_in  = (const float*)d_in[6];
  const float* b_in  = (const float*)d_in[7];
  const float* w_out = (const float*)d_in[8];
  const float* b_out = (const float*)d_in[9];
  const float* pnw   = (const float*)d_in[10];
  const float* pnb   = (const float*)d_in[11];
  float* out = (float*)d_out;

  // ws layout (u16 units)
  u16* ws   = (u16*)d_ws;
  u16* xnh  = ws;                  // 8M
  u16* kh   = xnh + 8388608;       // 8M
  u16* vTh  = kh  + 8388608;       // 8M  [b][d][token]
  u16* qh   = vTh + 8388608;       // 8M  (pre-scaled by 0.125)
  u16* yh   = qh  + 8388608;       // 2M
  u16* hh   = yh  + 2097152;       // 8M
  u16* eoTh = hh  + 8388608;       // 2M  [b][d][slot]
  u16* wch  = eoTh + 2097152;      // 4M: wk|wv|wq|sq(x0.125)|skq fp16
  u16* sqh  = wch + 3145728;
  u16* skh  = wch + 3670016;
  float* pbuf = (float*)(wch + 4194304);   // 8.4M floats (33.5 MB), dual-use
  float* pdb  = pbuf + 8388608;            // 131072 floats
  float* pacc = pbuf;                      // aliased (disjoint lifetime)

  // 1. fused: pre-norm -> fp16 + weights/slot tensors -> fp16
  ln_wcvt<<<10240, 256, 0, stream>>>(x, pnw, pnb, xnh, wk, wv, wq, sq, skq, wch);

  // 2. fused projections (m-major grid, BK=64)
  proj_f16<<<dim3(64, 24, 1), 256, 0, stream>>>(xnh, wch, kh, vTh, qh);

  // 3. dispatch attention, K-split 2: Q=sqh, K=kh, V=vTh -> partials -> yh
  flash_f16<false><<<dim3(8, 2, 64), 256, 0, stream>>>(
      sqh, 0L, (long)(S_ * DH_), (long)DH_,
      kh, (long)(L_ * D_), (long)DH_, (long)D_,
      vTh, (long)(L_ * D_), (long)(DH_ * L_), (long)L_,
      nullptr, 0L, 0L, 0L,
      pdb, pacc, S_, L_, 2);
  finalize_f16<<<8192, 256, 0, stream>>>(pdb, pacc, yh, 2, S_,
      (long)(S_ * D_), (long)DH_, (long)D_);

  // 4. experts
  expert_gemm<1><<<dim3(64, 1, 8), 512, 0, stream>>>(yh, w_in, b_in, hh, nullptr);
  expert_gemm<2><<<dim3(16, 4, 8), 512, 0, stream>>>(hh, w_out, nullptr, nullptr, pbuf);
  eo_reduce<<<2048, 256, 0, stream>>>(pbuf, b_out, eoTh);

  // 5. combine attention: Q=qh, K=skh, V=eoTh -> out f32
  flash_f16<true><<<dim3(32, 1, 64), 256, 0, stream>>>(
      qh, (long)(L_ * D_), (long)DH_, (long)D_,
      skh, 0L, (long)(S_ * DH_), (long)DH_,
      eoTh, (long)(S_ * D_), (long)(DH_ * S_), (long)S_,
      out, (long)(L_ * D_), (long)DH_, (long)D_,
      nullptr, nullptr, L_, S_, 1);
}

// Round 14
// 303.490 us; speedup vs baseline: 1.0520x; 1.0520x over previous
//
#include <hip/hip_runtime.h>
#include <hip/hip_bf16.h>

// SoftMoE fp16-MFMA pipeline. B=4 L=2048 D=1024 H=16 S=512 E=8 FF=4096 DH=64
#define B_  4
#define L_  2048
#define D_  1024
#define H_  16
#define S_  512
#define E_  8
#define FF_ 4096
#define DH_ 64

typedef _Float16 half8 __attribute__((ext_vector_type(8)));
typedef _Float16 half4v __attribute__((ext_vector_type(4)));
typedef float floatx4 __attribute__((ext_vector_type(4)));
typedef unsigned short u16;

__device__ inline u16 f2h(float v) {
  _Float16 x = (_Float16)v;
  return __builtin_bit_cast(u16, x);
}
__device__ inline float h2f(u16 v) {
  return (float)__builtin_bit_cast(_Float16, v);
}

__device__ inline void gload_lds16(const void* g, void* l) {
  __builtin_amdgcn_global_load_lds(
      (const __attribute__((address_space(1))) void*)g,
      (__attribute__((address_space(3))) void*)l, 16, 0, 0);
}

// swizzled index (u16 units): row stride 64 halfs (128B), XOR 16B granule by row&7
__device__ inline int swz(int row, int colh) {  // colh multiple of 8
  return row * 64 + (colh ^ ((row & 7) << 3));
}
__device__ inline int swz1(int row, int colh) { // arbitrary colh
  return row * 64 + ((colh & ~7) ^ ((row & 7) << 3)) + (colh & 7);
}

// ---------------- Fused LayerNorm + weight cvt -------------------------------
// blocks 0..8191: LN row -> fp16. blocks 8192..10239: cvt wk|wv|wq|sq*0.125|skq.
__global__ __launch_bounds__(256) void ln_wcvt(const float* __restrict__ x,
    const float* __restrict__ w, const float* __restrict__ bb,
    u16* __restrict__ xn,
    const float* __restrict__ w0, const float* __restrict__ w1,
    const float* __restrict__ w2, const float* __restrict__ sq,
    const float* __restrict__ skq, u16* __restrict__ dst) {
  int tid = threadIdx.x;
  if (blockIdx.x >= 8192) {
    long i = ((long)(blockIdx.x - 8192) * 256 + tid) * 8;
    const float* src; long off; float sc = 1.0f;
    if (i < 3145728) {
      int wsel = (int)(i >> 20);
      src = (wsel == 0) ? w0 : (wsel == 1) ? w1 : w2;
      off = i & 1048575;
    } else if (i < 3670016) {
      src = sq; off = i - 3145728; sc = 0.125f;
    } else {
      src = skq; off = i - 3670016;
    }
    float4 a = *(const float4*)(src + off);
    float4 b = *(const float4*)(src + off + 4);
    half8 h = { (_Float16)(a.x*sc), (_Float16)(a.y*sc), (_Float16)(a.z*sc), (_Float16)(a.w*sc),
                (_Float16)(b.x*sc), (_Float16)(b.y*sc), (_Float16)(b.z*sc), (_Float16)(b.w*sc) };
    *(half8*)(dst + i) = h;
    return;
  }
  int row = blockIdx.x;
  float4 v = ((const float4*)(x + (long)row * D_))[tid];
  float s = v.x + v.y + v.z + v.w;
  __shared__ float red[4];
  #pragma unroll
  for (int off = 32; off > 0; off >>= 1) s += __shfl_down(s, off);
  int wid = tid >> 6, lane = tid & 63;
  if (lane == 0) red[wid] = s;
  __syncthreads();
  float mean = (red[0] + red[1] + red[2] + red[3]) * (1.0f / D_);
  __syncthreads();
  float dx = v.x - mean, dy = v.y - mean, dz = v.z - mean, dw = v.w - mean;
  float s2 = dx*dx + dy*dy + dz*dz + dw*dw;
  #pragma unroll
  for (int off = 32; off > 0; off >>= 1) s2 += __shfl_down(s2, off);
  if (lane == 0) red[wid] = s2;
  __syncthreads();
  float var = (red[0] + red[1] + red[2] + red[3]) * (1.0f / D_);
  float rstd = rsqrtf(var + 1e-5f);
  float4 wv = ((const float4*)w)[tid];
  float4 bv = ((const float4*)bb)[tid];
  half4v o = { (_Float16)(dx * rstd * wv.x + bv.x),
               (_Float16)(dy * rstd * wv.y + bv.y),
               (_Float16)(dz * rstd * wv.z + bv.z),
               (_Float16)(dw * rstd * wv.w + bv.w) };
  *(half4v*)&xn[(long)row * D_ + tid * 4] = o;
}

// ---------------- Fused projections (fp16 weights, dbuf 2-phase, BK=32) ------
// grid (64 m, 24): wsel = by>>3 (k,v,q); n0 = (by&7)*128; m0 = bx*128.
// m-major dispatch keeps all blocks sharing an A-panel on one XCD's L2.
__global__ __launch_bounds__(256) void proj_f16(
    const u16* __restrict__ A, const u16* __restrict__ Wc,
    u16* __restrict__ kh, u16* __restrict__ vT, u16* __restrict__ qh) {
  const int wsel = blockIdx.y >> 3;
  const int n0 = (blockIdx.y & 7) * 128, m0 = blockIdx.x * 128;
  const u16* Bh = Wc + (long)wsel * 1048576;
  const int tid = threadIdx.x, l = tid & 63, w = tid >> 6;
  const int wr = w >> 1, wc = w & 1;
  __shared__ __align__(16) u16 As[2][128 * 32];
  __shared__ __align__(16) u16 Bs[2][128 * 32];
  floatx4 acc[4][4] = {};

  const int ck = (l & 3) ^ ((l >> 3) & 3);
  const long gaA0 = (long)(m0 + w * 32 + (l >> 2)) * D_ + ck * 8;
  const long gaA1 = gaA0 + 16 * D_;
  const long gaB0 = (long)(n0 + w * 32 + (l >> 2)) * D_ + ck * 8;
  const long gaB1 = gaB0 + 16 * D_;

  #define PSTAGE(buf, kt)                                          \
    do {                                                           \
      gload_lds16(A + gaA0 + (kt), &As[buf][(w * 32) * 32]);       \
      gload_lds16(A + gaA1 + (kt), &As[buf][(w * 32 + 16) * 32]);  \
      gload_lds16(Bh + gaB0 + (kt), &Bs[buf][(w * 32) * 32]);      \
      gload_lds16(Bh + gaB1 + (kt), &Bs[buf][(w * 32 + 16) * 32]); \
    } while (0)

  PSTAGE(0, 0);
  __syncthreads();

  int cur = 0;
  const int q = l >> 4;
  for (int t = 0; t < 32; ++t) {
    if (t < 31) PSTAGE(cur ^ 1, (t + 1) * 32);
    half8 af[4], bfr[4];
    #pragma unroll
    for (int fr = 0; fr < 4; ++fr) {
      int row = wr * 64 + fr * 16 + (l & 15);
      af[fr] = *(const half8*)&As[cur][row * 32 + ((q ^ ((row >> 1) & 3)) << 3)];
    }
    #pragma unroll
    for (int fc = 0; fc < 4; ++fc) {
      int rr = wc * 64 + fc * 16 + (l & 15);
      bfr[fc] = *(const half8*)&Bs[cur][rr * 32 + ((q ^ ((rr >> 1) & 3)) << 3)];
    }
    #pragma unroll
    for (int fr = 0; fr < 4; ++fr)
      #pragma unroll
      for (int fc = 0; fc < 4; ++fc)
        acc[fr][fc] = __builtin_amdgcn_mfma_f32_16x16x32_f16(af[fr], bfr[fc], acc[fr][fc], 0, 0, 0);
    __syncthreads();
    cur ^= 1;
  }
  #undef PSTAGE

  if (wsel == 1) {
    #pragma unroll
    for (int fr = 0; fr < 4; ++fr)
      #pragma unroll
      for (int fc = 0; fc < 4; ++fc) {
        int row = m0 + wr * 64 + fr * 16 + (l >> 4) * 4;
        int col = n0 + wc * 64 + fc * 16 + (l & 15);
        half4v o = { (_Float16)acc[fr][fc][0], (_Float16)acc[fr][fc][1],
                     (_Float16)acc[fr][fc][2], (_Float16)acc[fr][fc][3] };
        long idx = ((long)(row >> 11) * 1024 + col) * 2048 + (row & 2047);
        *(half4v*)&vT[idx] = o;
      }
  } else {
    u16* C = (wsel == 0) ? kh : qh;
    const float sc = (wsel == 2) ? 0.125f : 1.0f;
    #pragma unroll
    for (int fr = 0; fr < 4; ++fr)
      #pragma unroll
      for (int fc = 0; fc < 4; ++fc)
        #pragma unroll
        for (int r = 0; r < 4; ++r) {
          int row = m0 + wr * 64 + fr * 16 + (l >> 4) * 4 + r;
          int col = n0 + wc * 64 + fc * 16 + (l & 15);
          C[(long)row * D_ + col] = f2h(acc[fr][fc][r] * sc);
        }
  }
}

// ---------------- Expert GEMM: ring-3 LDS, counted vmcnt ---------------------
// MODE 1: h = relu2(y @ w_in[e]^T + b_in) -> fp16. grid (64,1,8)
// MODE 2: partial h @ w_out[e]^T (K-chunk 1024) -> fp16 partials. grid (16,4,8)
template<int MODE>
__global__ __launch_bounds__(512) void expert_gemm(
    const u16* __restrict__ A, const float* __restrict__ Bw,
    const float* __restrict__ bias, u16* __restrict__ Ch,
    u16* __restrict__ Cp) {
  constexpr int LDA = (MODE == 1) ? D_ : FF_;
  constexpr int LDB = (MODE == 1) ? D_ : FF_;
  const int e = blockIdx.z;
  const int n0 = blockIdx.x * 64;
  const int kc0 = (MODE == 2) ? blockIdx.y * 1024 : 0;
  const int tid = threadIdx.x, l = tid & 63, w = tid >> 6;
  const int wm = w >> 1, wn = w & 1;
  const int lr = l & 15, q = l >> 4;

  __shared__ __align__(16) u16  As[3][256 * 32];
  __shared__ __align__(16) float Bs[3][64 * 32];

  long asrc[2];
  #pragma unroll
  for (int i = 0; i < 2; ++i) {
    int ar = w * 32 + i * 16 + (l >> 2);
    long grow = (MODE == 1) ? ((long)(ar >> 6) * 512 + e * 64 + (ar & 63))
                            : (((long)(ar >> 6) * 8 + e) * 64 + (ar & 63));
    int ck = (l & 3) ^ (ar & 3);
    asrc[i] = grow * (long)LDA + kc0 + ck * 8;
  }
  const float* Bp = Bw + (long)e * (D_ * FF_);
  int brow = w * 8 + (l >> 3);
  int bck = (l & 7) ^ (brow & 7);
  long bsrc = (long)(n0 + brow) * LDB + kc0 + bck * 4;

  floatx4 acc[4][2] = {};

  #define STAGE(buf, kt)                                                 \
    do {                                                                 \
      gload_lds16(A + asrc[0] + (kt), &As[buf][(w * 32) * 32]);          \
      gload_lds16(A + asrc[1] + (kt), &As[buf][(w * 32 + 16) * 32]);     \
      gload_lds16(Bp + bsrc + (kt), &Bs[buf][(w * 8) * 32]);             \
    } while (0)

  STAGE(0, 0);
  STAGE(1, 32);

  int c0 = 0, c1 = 1, c2 = 2;
  for (int t = 0; t < 32; ++t) {
    if (t < 31) asm volatile("s_waitcnt vmcnt(3)" ::: "memory");
    else        asm volatile("s_waitcnt vmcnt(0)" ::: "memory");
    __builtin_amdgcn_s_barrier();
    if (t + 2 < 32) STAGE(c2, (t + 2) * 32);

    half8 af[4];
    #pragma unroll
    for (int fr = 0; fr < 4; ++fr) {
      int row = wm * 64 + fr * 16 + lr;
      af[fr] = *(const half8*)&As[c0][row * 32 + ((q ^ (row & 3)) << 3)];
    }
    half8 bf[2];
    #pragma unroll
    for (int fc = 0; fc < 2; ++fc) {
      int rn = wn * 32 + fc * 16 + lr;
      float4 x0 = *(const float4*)&Bs[c0][rn * 32 + (((2 * q) ^ (rn & 7)) << 2)];
      float4 x1 = *(const float4*)&Bs[c0][rn * 32 + (((2 * q + 1) ^ (rn & 7)) << 2)];
      bf[fc] = (half8){ (_Float16)x0.x, (_Float16)x0.y, (_Float16)x0.z, (_Float16)x0.w,
                        (_Float16)x1.x, (_Float16)x1.y, (_Float16)x1.z, (_Float16)x1.w };
    }
    #pragma unroll
    for (int fr = 0; fr < 4; ++fr)
      #pragma unroll
      for (int fc = 0; fc < 2; ++fc)
        acc[fr][fc] = __builtin_amdgcn_mfma_f32_16x16x32_f16(af[fr], bf[fc], acc[fr][fc], 0, 0, 0);

    int tmp = c0; c0 = c1; c1 = c2; c2 = tmp;
  }
  #undef STAGE

  #pragma unroll
  for (int fr = 0; fr < 4; ++fr)
    #pragma unroll
    for (int fc = 0; fc < 2; ++fc)
      #pragma unroll
      for (int r = 0; r < 4; ++r) {
        int ar = wm * 64 + fr * 16 + q * 4 + r;
        int col = n0 + wn * 32 + fc * 16 + lr;
        float val = acc[fr][fc][r];
        if constexpr (MODE == 1) {
          val += bias[e * FF_ + col];
          val = fmaxf(val, 0.f);
          val *= val;
          Ch[(((long)(ar >> 6) * 8 + e) * 64 + (ar & 63)) * FF_ + col] = f2h(val);
        } else {
          Cp[(((long)blockIdx.y * 8 + e) * 256 + ar) * 1024 + col] = f2h(val);
        }
      }
}

// ------- expert-out reduce: sum 4 fp16 K-split partials + bias -> eoT --------
__global__ __launch_bounds__(256) void eo_reduce(const u16* __restrict__ pb,
    const float* __restrict__ b_out, u16* __restrict__ eoT) {
  long j8 = (long)blockIdx.x * 256 + threadIdx.x;   // half8 index over 2M halfs
  long j = j8 * 8;
  float s[8] = {};
  #pragma unroll
  for (int c = 0; c < 4; ++c) {
    half8 t = *(const half8*)(pb + (long)c * 2097152 + j);
    #pragma unroll
    for (int i = 0; i < 8; ++i) s[i] += (float)t[i];
  }
  int e = (int)(j >> 18);
  int rem = (int)(j & 262143);
  int row = rem >> 10, col = rem & 1023;
  float4 bv0 = *(const float4*)(b_out + e * 1024 + col);
  float4 bv1 = *(const float4*)(b_out + e * 1024 + col + 4);
  s[0] += bv0.x; s[1] += bv0.y; s[2] += bv0.z; s[3] += bv0.w;
  s[4] += bv1.x; s[5] += bv1.y; s[6] += bv1.z; s[7] += bv1.w;
  int b = row >> 6;
  int slot = e * 64 + (row & 63);
  #pragma unroll
  for (int i = 0; i < 8; ++i) {
    long idx = ((long)b * 1024 + col + i) * 512 + slot;
    eoT[idx] = f2h(s[i]);
  }
}

// ---------------- MFMA flash attention v2: register-resident P ---------------
template<bool OF32>
__global__ __launch_bounds__(256) void flash_f16(
    const u16* __restrict__ Qg, long qB, long qH, long qR,
    const u16* __restrict__ Kg, long kB, long kH, long kR,
    const u16* __restrict__ VTg, long vB, long vH, long vR,
    void* __restrict__ Og, long oB, long oH, long oR,
    float* __restrict__ pd, float* __restrict__ pacc,
    int Nq, int Nk, int nC) {
  __shared__ __align__(16) u16 Ks[64 * 64];
  __shared__ __align__(16) u16 Vt[64 * 64];
  const int tid = threadIdx.x, l = tid & 63, w = tid >> 6;
  const int g = l >> 4, lq = l & 15;
  const int bh = blockIdx.z, b = bh >> 4, hd = bh & 15;
  const int q0 = blockIdx.x * 64 + w * 16;
  const int chunk = Nk / nC, k0 = blockIdx.y * chunk;

  half8 qf[2];
  #pragma unroll
  for (int ks = 0; ks < 2; ++ks)
    qf[ks] = *(const half8*)(Qg + b * qB + hd * qH +
                             (long)(q0 + lq) * qR + ks * 32 + g * 8);

  const int srow = l >> 3;
  const int scol = ((l & 7) ^ srow) * 8;
  const long kbase = b * kB + hd * kH;
  const long vbase = b * vB + hd * vH;

  float lrun = 0.f;
  floatx4 o[4] = {};

  for (int t = 0; t < chunk; t += 64) {
    #pragma unroll
    for (int i = 0; i < 2; ++i) {
      int u = i * 4 + w;
      gload_lds16(Kg + kbase + (long)(k0 + t + u * 8 + srow) * kR + scol,
                  &Ks[u * 8 * 64]);
      gload_lds16(VTg + vbase + (long)(u * 8 + srow) * vR + k0 + t + scol,
                  &Vt[u * 8 * 64]);
    }
    __syncthreads();

    floatx4 s[4];
    #pragma unroll
    for (int j = 0; j < 4; ++j) s[j] = (floatx4){0.f, 0.f, 0.f, 0.f};
    #pragma unroll
    for (int ks = 0; ks < 2; ++ks)
      #pragma unroll
      for (int j = 0; j < 4; ++j) {
        half8 kf = *(const half8*)&Ks[swz(j * 16 + lq, ks * 32 + g * 8)];
        s[j] = __builtin_amdgcn_mfma_f32_16x16x32_f16(kf, qf[ks], s[j], 0, 0, 0);
      }

    half4v pa[4];
    float rs = 0.f;
    #pragma unroll
    for (int j = 0; j < 4; ++j)
      #pragma unroll
      for (int r = 0; r < 4; ++r) {
        float p = __expf(s[j][r]);
        rs += p;
        pa[j][r] = (_Float16)p;
      }
    lrun += rs;

    #pragma unroll
    for (int j = 0; j < 4; ++j)
      #pragma unroll
      for (int n = 0; n < 4; ++n) {
        half4v vf = *(const half4v*)&Vt[swz1(n * 16 + lq, j * 16 + g * 4)];
        o[n] = __builtin_amdgcn_mfma_f32_16x16x16f16(pa[j], vf, o[n], 0, 0, 0);
      }
    __syncthreads();
  }

  lrun += __shfl_xor(lrun, 16);
  lrun += __shfl_xor(lrun, 32);

  if (nC == 1) {
    float inv = 1.0f / lrun;
    float invr[4];
    #pragma unroll
    for (int r = 0; r < 4; ++r) invr[r] = __shfl(inv, g * 4 + r);
    #pragma unroll
    for (int n = 0; n < 4; ++n)
      #pragma unroll
      for (int r = 0; r < 4; ++r) {
        int row = q0 + g * 4 + r;
        int dh = n * 16 + lq;
        float val = o[n][r] * invr[r];
        long off = b * oB + hd * oH + (long)row * oR + dh;
        if (OF32) ((float*)Og)[off] = val;
        else      ((u16*)Og)[off] = f2h(val);
      }
  } else {
    if (l < 16) pd[((long)bh * Nq + q0 + l) * nC + blockIdx.y] = lrun;
    #pragma unroll
    for (int r = 0; r < 4; ++r) {
      int row = q0 + g * 4 + r;
      long idx = ((long)bh * Nq + row) * nC + blockIdx.y;
      #pragma unroll
      for (int n = 0; n < 4; ++n)
        pacc[idx * 64 + n * 16 + lq] = o[n][r];
    }
  }
}

// ---------------- Flash finalize: sum nC chunk partials -> f16 out -----------
__global__ __launch_bounds__(256) void finalize_f16(
    const float* __restrict__ pd, const float* __restrict__ pacc,
    u16* __restrict__ outp, int nC, int Nq, long oB, long oH, long oR) {
  int tid = threadIdx.x;
  int row = blockIdx.x * 4 + (tid >> 6);
  int lane = tid & 63;
  long base = (long)row * nC;
  float Dn = 0.f, a = 0.f;
  for (int c = 0; c < nC; ++c) {
    Dn += pd[base + c];
    a += pacc[(base + c) * 64 + lane];
  }
  int bh = row / Nq, qrow = row - bh * Nq;
  int b = bh >> 4, h = bh & 15;
  outp[(long)b * oB + (long)h * oH + (long)qrow * oR + lane] = f2h(a / Dn);
}

extern "C" void kernel_launch(void* const* d_in, const int* in_sizes, int n_in,
                              void* d_out, int out_size, void* d_ws, size_t ws_size,
                              hipStream_t stream) {
  const float* x     = (const float*)d_in[0];
  const float* sq    = (const float*)d_in[1];
  const float* skq   = (const float*)d_in[2];
  const float* wk    = (const float*)d_in[3];
  const float* wv    = (const float*)d_in[4];
  const float* wq    = (const float*)d_in[5];
  const float* w_in  = (const float*)d_in[6];
  const float* b_in  = (const float*)d_in[7];
  const float* w_out = (const float*)d_in[8];
  const float* b_out = (const float*)d_in[9];
  const float* pnw   = (const float*)d_in[10];
  const float* pnb   = (const float*)d_in[11];
  float* out = (float*)d_out;

  // ws layout (u16 units)
  u16* ws   = (u16*)d_ws;
  u16* xnh  = ws;                  // 8M
  u16* kh   = xnh + 8388608;       // 8M
  u16* vTh  = kh  + 8388608;       // 8M  [b][d][token]
  u16* qh   = vTh + 8388608;       // 8M  (pre-scaled by 0.125)
  u16* yh   = qh  + 8388608;       // 2M
  u16* hh   = yh  + 2097152;       // 8M
  u16* eoTh = hh  + 8388608;       // 2M  [b][d][slot]
  u16* wch  = eoTh + 2097152;      // 4M: wk|wv|wq|sq(x0.125)|skq fp16
  u16* sqh  = wch + 3145728;
  u16* skh  = wch + 3670016;
  u16* pb16 = wch + 4194304;               // 8M u16: 4 fp16 expert-out partials
  float* pacc = (float*)pb16;              // alias (disjoint lifetime w/ pb16)
  float* pdb  = (float*)(pb16 + 8388608);  // 131072 floats

  // 1. fused: pre-norm -> fp16 + weights/slot tensors -> fp16
  ln_wcvt<<<10240, 256, 0, stream>>>(x, pnw, pnb, xnh, wk, wv, wq, sq, skq, wch);

  // 2. fused projections (m-major grid, BK=32)
  proj_f16<<<dim3(64, 24, 1), 256, 0, stream>>>(xnh, wch, kh, vTh, qh);

  // 3. dispatch attention, K-split 2: Q=sqh, K=kh, V=vTh -> partials -> yh
  flash_f16<false><<<dim3(8, 2, 64), 256, 0, stream>>>(
      sqh, 0L, (long)(S_ * DH_), (long)DH_,
      kh, (long)(L_ * D_), (long)DH_, (long)D_,
      vTh, (long)(L_ * D_), (long)(DH_ * L_), (long)L_,
      nullptr, 0L, 0L, 0L,
      pdb, pacc, S_, L_, 2);
  finalize_f16<<<8192, 256, 0, stream>>>(pdb, pacc, yh, 2, S_,
      (long)(S_ * D_), (long)DH_, (long)D_);

  // 4. experts (fp16 K-split partials)
  expert_gemm<1><<<dim3(64, 1, 8), 512, 0, stream>>>(yh, w_in, b_in, hh, nullptr);
  expert_gemm<2><<<dim3(16, 4, 8), 512, 0, stream>>>(hh, w_out, nullptr, nullptr, pb16);
  eo_reduce<<<1024, 256, 0, stream>>>(pb16, b_out, eoTh);

  // 5. combine attention: Q=qh, K=skh, V=eoTh -> out f32
  flash_f16<true><<<dim3(32, 1, 64), 256, 0, stream>>>(
      qh, (long)(L_ * D_), (long)DH_, (long)D_,
      skh, 0L, (long)(S_ * DH_), (long)DH_,
      eoTh, (long)(S_ * D_), (long)(DH_ * S_), (long)S_,
      out, (long)(L_ * D_), (long)DH_, (long)D_,
      nullptr, nullptr, L_, S_, 1);
}